// Round 8
// baseline (135.849 us; speedup 1.0000x reference)
//
#include <hip/hip_runtime.h>
#include <hip/hip_bf16.h>

#define BATCH 16384
#define DIM   512
#define NPG   64
#define NPAIR 4096
#define NA    128
#define GEMM_BLOCKS 1024

typedef float f32x4 __attribute__((ext_vector_type(4)));
typedef short s16x8 __attribute__((ext_vector_type(8)));
typedef unsigned short u16;

static __device__ __forceinline__ u16 f2bf(float f) {
    union { float f; unsigned u; } v; v.f = f;
    unsigned r = (v.u + 0x7FFFu + ((v.u >> 16) & 1u)) >> 16;
    return (u16)r;
}

// kA: A[j][d] = proto[j] . W[d][koff:koff+512], K-split x2 across lane pairs.
__global__ __launch_bounds__(256) void kA_mixA(const float* __restrict__ proto,
                                               const float* __restrict__ W,
                                               float* __restrict__ Af,
                                               u16* __restrict__ Ab) {
    int gid = blockIdx.x * 256 + threadIdx.x;
    int h = gid & 1;
    int j = (gid >> 1) & 127;
    int d = gid >> 8;
    int koff = (j < NPG ? 0 : DIM) + h * (DIM / 2);
    const float4* pr = (const float4*)(proto + j * DIM + h * (DIM / 2));
    const float4* wr = (const float4*)(W + d * (2 * DIM) + koff);
    float a0 = 0.f, a1 = 0.f, a2 = 0.f, a3 = 0.f;
#pragma unroll 4
    for (int k4 = 0; k4 < DIM / 8; ++k4) {
        float4 p = pr[k4], w = wr[k4];
        a0 += p.x * w.x; a1 += p.y * w.y; a2 += p.z * w.z; a3 += p.w * w.w;
    }
    float a = (a0 + a1) + (a2 + a3);
    a += __shfl_xor(a, 1);
    if (h == 0) {
        Af[j * DIM + d] = a;
        Ab[j * DIM + d] = f2bf(a);
    }
}

// kB: GEMM blocks: 16-row slab of U = X@A^T, x staged bf16 in swizzled LDS,
// rb fused. Tail blocks: pp pairs.
__global__ __launch_bounds__(512, 4) void kB_main(const float* __restrict__ x,
                                                  const u16* __restrict__ Ab,
                                                  const float* __restrict__ Af,
                                                  const float* __restrict__ bm,
                                                  float* __restrict__ U,
                                                  float* __restrict__ rb,
                                                  float* __restrict__ pp) {
    __shared__ u16   xsb[16 * 512];
    __shared__ float xxs[16], ws2[16];
    int bid = blockIdx.x;
    int t = threadIdx.x;
    int lane = t & 63;
    int w = t >> 6;

    if (bid < GEMM_BLOCKS) {
        int m0 = bid * 16;
        int row = t >> 5;
        int c0 = (t & 31) * 4;
        const float* xrow = x + (size_t)(m0 + row) * DIM;
        float xx = 0.f, wdot = 0.f;
#pragma unroll
        for (int i = 0; i < 4; ++i) {
            int col = c0 + i * 128;
            float4 v = *(const float4*)(xrow + col);
            float4 b = *(const float4*)(bm + col);
            xx   += v.x * v.x + v.y * v.y + v.z * v.z + v.w * v.w;
            wdot += v.x * b.x + v.y * b.y + v.z * b.z + v.w * b.w;
            ushort4 hv;
            hv.x = f2bf(v.x); hv.y = f2bf(v.y); hv.z = f2bf(v.z); hv.w = f2bf(v.w);
            int byte = (row * 1024 + col * 2) ^ ((row & 7) << 4);
            *(ushort4*)((char*)xsb + byte) = hv;
        }
#pragma unroll
        for (int off = 16; off > 0; off >>= 1) {
            xx   += __shfl_xor(xx, off);
            wdot += __shfl_xor(wdot, off);
        }
        if ((t & 31) == 0) { xxs[row] = xx; ws2[row] = wdot; }
        __syncthreads();
        if (t < 16) rb[m0 + t] = xxs[t] - 2.0f * ws2[t];

        int r = lane & 15, g = lane >> 4;
        int ct = w;
        f32x4 acc = (f32x4){0.f, 0.f, 0.f, 0.f};
        const u16* brow = Ab + (size_t)(ct * 16 + r) * DIM;
#pragma unroll
        for (int k0 = 0; k0 < 16; ++k0) {
            int byte = (r * 1024 + k0 * 64 + g * 16) ^ ((r & 7) << 4);
            s16x8 af = *(const s16x8*)((const char*)xsb + byte);
            s16x8 bf = *(const s16x8*)(brow + k0 * 32 + g * 8);
            acc = __builtin_amdgcn_mfma_f32_16x16x32_bf16(af, bf, acc, 0, 0, 0);
        }
#pragma unroll
        for (int rr = 0; rr < 4; ++rr)
            U[(size_t)(m0 + g * 4 + rr) * NA + ct * 16 + r] = acc[rr];
    } else {
        int pidx = (bid - GEMM_BLOCKS) * 8 + w;
        int j = pidx >> 6, l = pidx & 63;
        const float4* r0 = (const float4*)(Af + j * DIM);
        const float4* r1 = (const float4*)(Af + (NPG + l) * DIM);
        const float4* bb = (const float4*)bm;
        float acc = 0.f;
#pragma unroll
        for (int i = 0; i < 2; ++i) {
            int idx = lane * 2 + i;
            float4 v0 = r0[idx], v1 = r1[idx], vb = bb[idx];
            float s;
            s = v0.x + v1.x + vb.x; acc += s * s;
            s = v0.y + v1.y + vb.y; acc += s * s;
            s = v0.z + v1.z + vb.z; acc += s * s;
            s = v0.w + v1.w + vb.w; acc += s * s;
        }
#pragma unroll
        for (int off = 32; off > 0; off >>= 1) acc += __shfl_xor(acc, off);
        if (lane == 0) pp[pidx] = acc;
    }
}

// kC: out[b][j*64+l] = pp[p] + rb[b] - 2*(U[b][j] + U[b][64+l])
__global__ __launch_bounds__(256) void kC_out(const float* __restrict__ U,
                                              const float* __restrict__ rb,
                                              const float* __restrict__ pp,
                                              float* __restrict__ out) {
    int t = threadIdx.x;
    int m0 = blockIdx.x * 4;
#pragma unroll
    for (int rr = 0; rr < 4; ++rr) {
        int brow = m0 + rr;
        float base0 = rb[brow];
        const float* Ur = U + (size_t)brow * NA;
        float* orow = out + (size_t)brow * NPAIR;
#pragma unroll
        for (int i = 0; i < 4; ++i) {
            int idx = (i * 256 + t) * 4;
            int j = idx >> 6, l = idx & 63;
            float uj = Ur[j];
            float4 v4 = *(const float4*)(Ur + NPG + l);
            float4 p4 = *(const float4*)(pp + idx);
            float s = base0 - 2.0f * uj;
            float4 o;
            o.x = s + p4.x - 2.0f * v4.x;
            o.y = s + p4.y - 2.0f * v4.y;
            o.z = s + p4.z - 2.0f * v4.z;
            o.w = s + p4.w - 2.0f * v4.w;
            *(float4*)(orow + idx) = o;
        }
    }
}

extern "C" void kernel_launch(void* const* d_in, const int* in_sizes, int n_in,
                              void* d_out, int out_size, void* d_ws, size_t ws_size,
                              hipStream_t stream) {
    const float* x     = (const float*)d_in[0];
    const float* proto = (const float*)d_in[1];
    const float* Wmix  = (const float*)d_in[2];
    const float* bmix  = (const float*)d_in[3];
    float* out = (float*)d_out;

    float* ws = (float*)d_ws;
    float* Af = ws;
    float* pp = ws + 65536;
    float* rb = ws + 69632;
    float* U  = ws + 86016;
    u16*   Ab = (u16*)(ws + 86016 + 16384 * 128);

    kA_mixA<<<512, 256, 0, stream>>>(proto, Wmix, Af, Ab);
    // DIAGNOSTIC: kB launched 3x (idempotent — identical output).
    // (dur - R4's 100.5) == 2 x (kB cost + launch overhead).
    kB_main<<<GEMM_BLOCKS + 512, 512, 0, stream>>>(x, Ab, Af, bmix, U, rb, pp);
    kB_main<<<GEMM_BLOCKS + 512, 512, 0, stream>>>(x, Ab, Af, bmix, U, rb, pp);
    kB_main<<<GEMM_BLOCKS + 512, 512, 0, stream>>>(x, Ab, Af, bmix, U, rb, pp);
    kC_out <<<4096, 256, 0, stream>>>(U, rb, pp, out);
}

// Round 9
// 125.666 us; speedup vs baseline: 1.0810x; 1.0810x over previous
//
#include <hip/hip_runtime.h>
#include <hip/hip_bf16.h>

#define BATCH 16384
#define DIM   512
#define NPG   64
#define NPAIR 4096
#define NA    128

typedef float f32x4 __attribute__((ext_vector_type(4)));
typedef short s16x8 __attribute__((ext_vector_type(8)));
typedef unsigned short u16;

static __device__ __forceinline__ u16 f2bf(float f) {
    union { float f; unsigned u; } v; v.f = f;
    unsigned r = (v.u + 0x7FFFu + ((v.u >> 16) & 1u)) >> 16;
    return (u16)r;
}

// kA: A[j][d] = proto[j] . W[d][koff:koff+512], K-split x2 across lane pairs.
__global__ __launch_bounds__(256) void kA_mixA(const float* __restrict__ proto,
                                               const float* __restrict__ W,
                                               float* __restrict__ Af,
                                               u16* __restrict__ Ab) {
    int gid = blockIdx.x * 256 + threadIdx.x;
    int h = gid & 1;
    int j = (gid >> 1) & 127;
    int d = gid >> 8;
    int koff = (j < NPG ? 0 : DIM) + h * (DIM / 2);
    const float4* pr = (const float4*)(proto + j * DIM + h * (DIM / 2));
    const float4* wr = (const float4*)(W + d * (2 * DIM) + koff);
    float a0 = 0.f, a1 = 0.f, a2 = 0.f, a3 = 0.f;
#pragma unroll 4
    for (int k4 = 0; k4 < DIM / 8; ++k4) {
        float4 p = pr[k4], w = wr[k4];
        a0 += p.x * w.x; a1 += p.y * w.y; a2 += p.z * w.z; a3 += p.w * w.w;
    }
    float a = (a0 + a1) + (a2 + a3);
    a += __shfl_xor(a, 1);
    if (h == 0) {
        Af[j * DIM + d] = a;
        Ab[j * DIM + d] = f2bf(a);
    }
}

// k2: pp[j*64+l] = || A[j] + A[64+l] + b ||^2   (one wave per pair)
__global__ __launch_bounds__(256) void k2_pp(const float* __restrict__ Af,
                                             const float* __restrict__ bm,
                                             float* __restrict__ pp) {
    int wave = (blockIdx.x * blockDim.x + threadIdx.x) >> 6;  // 4096 waves
    int lane = threadIdx.x & 63;
    int j = wave >> 6, l = wave & 63;
    const float4* r0 = (const float4*)(Af + j * DIM);
    const float4* r1 = (const float4*)(Af + (NPG + l) * DIM);
    const float4* bb = (const float4*)bm;
    float acc = 0.f;
#pragma unroll
    for (int i = 0; i < 2; ++i) {
        int idx = lane * 2 + i;
        float4 v0 = r0[idx], v1 = r1[idx], vb = bb[idx];
        float s;
        s = v0.x + v1.x + vb.x; acc += s * s;
        s = v0.y + v1.y + vb.y; acc += s * s;
        s = v0.z + v1.z + vb.z; acc += s * s;
        s = v0.w + v1.w + vb.w; acc += s * s;
    }
#pragma unroll
    for (int off = 32; off > 0; off >>= 1) acc += __shfl_xor(acc, off);
    if (lane == 0) pp[wave] = acc;
}

// kFC: fused GEMM+epilogue at kC geometry. 4096 blocks x 256 threads, 4 rows
// per block, 16 blocks/CU queued (2x turnover for phase overlap).
// NO min-waves launch_bounds clamp (R6 lesson: (256,8) => 64-VGPR spills).
// Phase1: wave w stages x-row w as bf16 in LDS + computes rb[w] inline.
// Phase2: waves do 16x16x32 MFMA, A-side rows 0..3 valid, U-tile -> LDS.
// Phase3: kC epilogue verbatim, U/rb from LDS. U never touches HBM.
__global__ __launch_bounds__(256) void kFC(const float* __restrict__ x,
                                           const u16* __restrict__ Ab,
                                           const float* __restrict__ bm,
                                           const float* __restrict__ pp,
                                           float* __restrict__ out) {
    __shared__ u16   xsb[4 * DIM];     // 4 KB bf16 x-slab
    __shared__ float Ut[4][NA];        // 2 KB
    __shared__ float rbl[4];
    int t = threadIdx.x;
    int lane = t & 63;
    int w = t >> 6;                    // wave = row index 0..3
    int m0 = blockIdx.x * 4;

    // ---- phase 1: wave w stages row m0+w, computes rb
    {
        const float* xrow = x + (size_t)(m0 + w) * DIM;
        int c0 = lane * 8;
        float4 v0 = *(const float4*)(xrow + c0);
        float4 v1 = *(const float4*)(xrow + c0 + 4);
        float4 b0 = *(const float4*)(bm + c0);
        float4 b1 = *(const float4*)(bm + c0 + 4);
        float xx = v0.x * v0.x + v0.y * v0.y + v0.z * v0.z + v0.w * v0.w
                 + v1.x * v1.x + v1.y * v1.y + v1.z * v1.z + v1.w * v1.w;
        float wd = v0.x * b0.x + v0.y * b0.y + v0.z * b0.z + v0.w * b0.w
                 + v1.x * b1.x + v1.y * b1.y + v1.z * b1.z + v1.w * b1.w;
        s16x8 hv;
        hv[0] = (short)f2bf(v0.x); hv[1] = (short)f2bf(v0.y);
        hv[2] = (short)f2bf(v0.z); hv[3] = (short)f2bf(v0.w);
        hv[4] = (short)f2bf(v1.x); hv[5] = (short)f2bf(v1.y);
        hv[6] = (short)f2bf(v1.z); hv[7] = (short)f2bf(v1.w);
        *(s16x8*)(xsb + w * DIM + c0) = hv;
#pragma unroll
        for (int off = 32; off > 0; off >>= 1) {
            xx += __shfl_xor(xx, off);
            wd += __shfl_xor(wd, off);
        }
        if (lane == 0) rbl[w] = xx - 2.0f * wd;
    }
    __syncthreads();

    // ---- phase 2: MFMA. Wave w owns U-cols [w*32, w*32+32) (ct = 2w, 2w+1).
    {
        int r = lane & 15, g = lane >> 4;
        f32x4 acc0 = (f32x4){0.f, 0.f, 0.f, 0.f};
        f32x4 acc1 = (f32x4){0.f, 0.f, 0.f, 0.f};
        const u16* b0p = Ab + (size_t)((w * 2 + 0) * 16 + r) * DIM;
        const u16* b1p = Ab + (size_t)((w * 2 + 1) * 16 + r) * DIM;
        const u16* ax  = xsb + (r & 3) * DIM;   // rows 4..15 feed dup data (discarded)
#pragma unroll
        for (int k0 = 0; k0 < 16; ++k0) {
            s16x8 af = *(const s16x8*)(ax + k0 * 32 + g * 8);
            s16x8 f0 = *(const s16x8*)(b0p + k0 * 32 + g * 8);
            s16x8 f1 = *(const s16x8*)(b1p + k0 * 32 + g * 8);
            acc0 = __builtin_amdgcn_mfma_f32_16x16x32_bf16(af, f0, acc0, 0, 0, 0);
            acc1 = __builtin_amdgcn_mfma_f32_16x16x32_bf16(af, f1, acc1, 0, 0, 0);
        }
        // C/D: col = lane&15, row = g*4+reg. Only rows 0..3 (g==0) are real.
        if (g == 0) {
#pragma unroll
            for (int rr = 0; rr < 4; ++rr) {
                Ut[rr][(w * 2 + 0) * 16 + r] = acc0[rr];
                Ut[rr][(w * 2 + 1) * 16 + r] = acc1[rr];
            }
        }
    }
    __syncthreads();

    // ---- phase 3: kC epilogue (verbatim), U/rb from LDS.
#pragma unroll
    for (int rr = 0; rr < 4; ++rr) {
        float base0 = rbl[rr];
        const float* Ur = Ut[rr];
        float* orow = out + (size_t)(m0 + rr) * NPAIR;
#pragma unroll
        for (int i = 0; i < 4; ++i) {
            int idx = (i * 256 + t) * 4;
            int j = idx >> 6, l = idx & 63;
            float uj = Ur[j];
            float4 v4 = *(const float4*)(Ur + NPG + l);
            float4 p4 = *(const float4*)(pp + idx);
            float s = base0 - 2.0f * uj;
            float4 o;
            o.x = s + p4.x - 2.0f * v4.x;
            o.y = s + p4.y - 2.0f * v4.y;
            o.z = s + p4.z - 2.0f * v4.z;
            o.w = s + p4.w - 2.0f * v4.w;
            *(float4*)(orow + idx) = o;
        }
    }
}

extern "C" void kernel_launch(void* const* d_in, const int* in_sizes, int n_in,
                              void* d_out, int out_size, void* d_ws, size_t ws_size,
                              hipStream_t stream) {
    const float* x     = (const float*)d_in[0];   // [16384, 512]
    const float* proto = (const float*)d_in[1];   // [2, 64, 512] -> flat [128, 512]
    const float* Wmix  = (const float*)d_in[2];   // [512, 1024]
    const float* bmix  = (const float*)d_in[3];   // [512]
    float* out = (float*)d_out;

    float* ws = (float*)d_ws;
    float* Af = ws;                         // 65536 f32
    float* pp = ws + 65536;                 // 4096 f32
    u16*   Ab = (u16*)(ws + 65536 + 4096);  // 65536 bf16

    kA_mixA<<<512, 256, 0, stream>>>(proto, Wmix, Af, Ab);
    k2_pp  <<<1024, 256, 0, stream>>>(Af, bmix, pp);
    kFC    <<<4096, 256, 0, stream>>>(x, Ab, bmix, pp, out);
}

// Round 10
// 100.626 us; speedup vs baseline: 1.3500x; 1.2488x over previous
//
#include <hip/hip_runtime.h>
#include <hip/hip_bf16.h>

#define BATCH 16384
#define DIM   512
#define NPG   64
#define NPAIR 4096
#define NA    128
#define GEMM_BLOCKS 1024

typedef float f32x4 __attribute__((ext_vector_type(4)));
typedef short s16x8 __attribute__((ext_vector_type(8)));
typedef unsigned short u16;

static __device__ __forceinline__ u16 f2bf(float f) {
    union { float f; unsigned u; } v; v.f = f;
    unsigned r = (v.u + 0x7FFFu + ((v.u >> 16) & 1u)) >> 16;
    return (u16)r;
}

// kA: A[j][d] = proto[j] . W[d][koff:koff+512], K-split x2 across lane pairs.
__global__ __launch_bounds__(256) void kA_mixA(const float* __restrict__ proto,
                                               const float* __restrict__ W,
                                               float* __restrict__ Af,
                                               u16* __restrict__ Ab) {
    int gid = blockIdx.x * 256 + threadIdx.x;
    int h = gid & 1;
    int j = (gid >> 1) & 127;
    int d = gid >> 8;
    int koff = (j < NPG ? 0 : DIM) + h * (DIM / 2);
    const float4* pr = (const float4*)(proto + j * DIM + h * (DIM / 2));
    const float4* wr = (const float4*)(W + d * (2 * DIM) + koff);
    float a0 = 0.f, a1 = 0.f, a2 = 0.f, a3 = 0.f;
#pragma unroll 4
    for (int k4 = 0; k4 < DIM / 8; ++k4) {
        float4 p = pr[k4], w = wr[k4];
        a0 += p.x * w.x; a1 += p.y * w.y; a2 += p.z * w.z; a3 += p.w * w.w;
    }
    float a = (a0 + a1) + (a2 + a3);
    a += __shfl_xor(a, 1);
    if (h == 0) {
        Af[j * DIM + d] = a;
        Ab[j * DIM + d] = f2bf(a);
    }
}

// kB: 256-thread blocks. GEMM blocks (bid<1024): 16-row slab of U = X@A^T,
// x staged bf16 in swizzled LDS, rb fused; 4 waves x 2 col-tiles each (2
// independent MFMA chains/iter for MLP against L2 latency). Tail blocks:
// pp pairs, 4 per block.
__global__ __launch_bounds__(256) void kB_main(const float* __restrict__ x,
                                               const u16* __restrict__ Ab,
                                               const float* __restrict__ Af,
                                               const float* __restrict__ bm,
                                               float* __restrict__ U,
                                               float* __restrict__ rb,
                                               float* __restrict__ pp) {
    __shared__ u16   xsb[16 * 512];    // 16 KB swizzled bf16 slab
    __shared__ float xxs[16], ws2[16];
    int bid = blockIdx.x;
    int t = threadIdx.x;
    int lane = t & 63;
    int w = t >> 6;

    if (bid < GEMM_BLOCKS) {
        int m0 = bid * 16;
        // ---- staging: 16 threads per row, 8 float4 each
        int row = t >> 4;
        int c0 = (t & 15) * 4;
        const float* xrow = x + (size_t)(m0 + row) * DIM;
        float xx = 0.f, wdot = 0.f;
#pragma unroll
        for (int i = 0; i < 8; ++i) {
            int col = c0 + i * 64;
            float4 v = *(const float4*)(xrow + col);
            float4 b = *(const float4*)(bm + col);
            xx   += v.x * v.x + v.y * v.y + v.z * v.z + v.w * v.w;
            wdot += v.x * b.x + v.y * b.y + v.z * b.z + v.w * b.w;
            ushort4 hv;
            hv.x = f2bf(v.x); hv.y = f2bf(v.y); hv.z = f2bf(v.z); hv.w = f2bf(v.w);
            int byte = (row * 1024 + col * 2) ^ ((row & 7) << 4);
            *(ushort4*)((char*)xsb + byte) = hv;
        }
        // reduce within the 16-thread group that owns this row
#pragma unroll
        for (int off = 8; off > 0; off >>= 1) {
            xx   += __shfl_xor(xx, off);
            wdot += __shfl_xor(wdot, off);
        }
        if ((t & 15) == 0) { xxs[row] = xx; ws2[row] = wdot; }
        __syncthreads();
        if (t < 16) rb[m0 + t] = xxs[t] - 2.0f * ws2[t];

        // ---- MFMA: wave w owns col-tiles ct = 2w, 2w+1 (two chains)
        int r = lane & 15, g = lane >> 4;
        f32x4 acc0 = (f32x4){0.f, 0.f, 0.f, 0.f};
        f32x4 acc1 = (f32x4){0.f, 0.f, 0.f, 0.f};
        const u16* b0p = Ab + (size_t)((w * 2 + 0) * 16 + r) * DIM;
        const u16* b1p = Ab + (size_t)((w * 2 + 1) * 16 + r) * DIM;
#pragma unroll
        for (int k0 = 0; k0 < 16; ++k0) {
            int byte = (r * 1024 + k0 * 64 + g * 16) ^ ((r & 7) << 4);
            s16x8 af = *(const s16x8*)((const char*)xsb + byte);
            s16x8 f0 = *(const s16x8*)(b0p + k0 * 32 + g * 8);
            s16x8 f1 = *(const s16x8*)(b1p + k0 * 32 + g * 8);
            acc0 = __builtin_amdgcn_mfma_f32_16x16x32_bf16(af, f0, acc0, 0, 0, 0);
            acc1 = __builtin_amdgcn_mfma_f32_16x16x32_bf16(af, f1, acc1, 0, 0, 0);
        }
        // C/D: col = lane&15 -> A-row, row = g*4+reg -> x-row
#pragma unroll
        for (int rr = 0; rr < 4; ++rr) {
            U[(size_t)(m0 + g * 4 + rr) * NA + (w * 2 + 0) * 16 + r] = acc0[rr];
            U[(size_t)(m0 + g * 4 + rr) * NA + (w * 2 + 1) * 16 + r] = acc1[rr];
        }
    } else {
        // ---- pp tail: 4 pairs per block (one per wave)
        int pidx = (bid - GEMM_BLOCKS) * 4 + w;    // [0, 4096)
        int j = pidx >> 6, l = pidx & 63;
        const float4* r0 = (const float4*)(Af + j * DIM);
        const float4* r1 = (const float4*)(Af + (NPG + l) * DIM);
        const float4* bb = (const float4*)bm;
        float acc = 0.f;
#pragma unroll
        for (int i = 0; i < 2; ++i) {
            int idx = lane * 2 + i;
            float4 v0 = r0[idx], v1 = r1[idx], vb = bb[idx];
            float s;
            s = v0.x + v1.x + vb.x; acc += s * s;
            s = v0.y + v1.y + vb.y; acc += s * s;
            s = v0.z + v1.z + vb.z; acc += s * s;
            s = v0.w + v1.w + vb.w; acc += s * s;
        }
#pragma unroll
        for (int off = 32; off > 0; off >>= 1) acc += __shfl_xor(acc, off);
        if (lane == 0) pp[pidx] = acc;
    }
}

// kC: out[b][j*64+l] = pp[p] + rb[b] - 2*(U[b][j] + U[b][64+l])
// BYTE-IDENTICAL to round 4 (measured at the write floor).
__global__ __launch_bounds__(256) void kC_out(const float* __restrict__ U,
                                              const float* __restrict__ rb,
                                              const float* __restrict__ pp,
                                              float* __restrict__ out) {
    int t = threadIdx.x;
    int m0 = blockIdx.x * 4;
#pragma unroll
    for (int rr = 0; rr < 4; ++rr) {
        int brow = m0 + rr;
        float base0 = rb[brow];
        const float* Ur = U + (size_t)brow * NA;
        float* orow = out + (size_t)brow * NPAIR;
#pragma unroll
        for (int i = 0; i < 4; ++i) {
            int idx = (i * 256 + t) * 4;
            int j = idx >> 6, l = idx & 63;
            float uj = Ur[j];
            float4 v4 = *(const float4*)(Ur + NPG + l);
            float4 p4 = *(const float4*)(pp + idx);
            float s = base0 - 2.0f * uj;
            float4 o;
            o.x = s + p4.x - 2.0f * v4.x;
            o.y = s + p4.y - 2.0f * v4.y;
            o.z = s + p4.z - 2.0f * v4.z;
            o.w = s + p4.w - 2.0f * v4.w;
            *(float4*)(orow + idx) = o;
        }
    }
}

extern "C" void kernel_launch(void* const* d_in, const int* in_sizes, int n_in,
                              void* d_out, int out_size, void* d_ws, size_t ws_size,
                              hipStream_t stream) {
    const float* x     = (const float*)d_in[0];
    const float* proto = (const float*)d_in[1];
    const float* Wmix  = (const float*)d_in[2];
    const float* bmix  = (const float*)d_in[3];
    float* out = (float*)d_out;

    float* ws = (float*)d_ws;
    float* Af = ws;
    float* pp = ws + 65536;
    float* rb = ws + 69632;
    float* U  = ws + 86016;
    u16*   Ab = (u16*)(ws + 86016 + 16384 * 128);

    kA_mixA<<<512, 256, 0, stream>>>(proto, Wmix, Af, Ab);
    kB_main<<<GEMM_BLOCKS + 1024, 256, 0, stream>>>(x, Ab, Af, bmix, U, rb, pp);
    kC_out <<<4096, 256, 0, stream>>>(U, rb, pp, out);
}

// Round 11
// 92.569 us; speedup vs baseline: 1.4675x; 1.0870x over previous
//
#include <hip/hip_runtime.h>
#include <hip/hip_bf16.h>

#define BATCH 16384
#define DIM   512
#define NPG   64
#define NPAIR 4096
#define NA    128

typedef float f32x4 __attribute__((ext_vector_type(4)));
typedef short s16x8 __attribute__((ext_vector_type(8)));
typedef unsigned short u16;

static __device__ __forceinline__ u16 f2bf(float f) {
    union { float f; unsigned u; } v; v.f = f;
    unsigned r = (v.u + 0x7FFFu + ((v.u >> 16) & 1u)) >> 16;
    return (u16)r;
}

// kA: A[j][d] = proto[j] . W[d][koff:koff+512], K-split x2 across lane pairs.
__global__ __launch_bounds__(256) void kA_mixA(const float* __restrict__ proto,
                                               const float* __restrict__ W,
                                               float* __restrict__ Af,
                                               u16* __restrict__ Ab) {
    int gid = blockIdx.x * 256 + threadIdx.x;
    int h = gid & 1;
    int j = (gid >> 1) & 127;
    int d = gid >> 8;
    int koff = (j < NPG ? 0 : DIM) + h * (DIM / 2);
    const float4* pr = (const float4*)(proto + j * DIM + h * (DIM / 2));
    const float4* wr = (const float4*)(W + d * (2 * DIM) + koff);
    float a0 = 0.f, a1 = 0.f, a2 = 0.f, a3 = 0.f;
#pragma unroll 4
    for (int k4 = 0; k4 < DIM / 8; ++k4) {
        float4 p = pr[k4], w = wr[k4];
        a0 += p.x * w.x; a1 += p.y * w.y; a2 += p.z * w.z; a3 += p.w * w.w;
    }
    float a = (a0 + a1) + (a2 + a3);
    a += __shfl_xor(a, 1);
    if (h == 0) {
        Af[j * DIM + d] = a;
        Ab[j * DIM + d] = f2bf(a);
    }
}

// k2: pp[j*64+l] = || A[j] + A[64+l] + b ||^2   (one wave per pair)
__global__ __launch_bounds__(256) void k2_pp(const float* __restrict__ Af,
                                             const float* __restrict__ bm,
                                             float* __restrict__ pp) {
    int wave = (blockIdx.x * blockDim.x + threadIdx.x) >> 6;  // 4096 waves
    int lane = threadIdx.x & 63;
    int j = wave >> 6, l = wave & 63;
    const float4* r0 = (const float4*)(Af + j * DIM);
    const float4* r1 = (const float4*)(Af + (NPG + l) * DIM);
    const float4* bb = (const float4*)bm;
    float acc = 0.f;
#pragma unroll
    for (int i = 0; i < 2; ++i) {
        int idx = lane * 2 + i;
        float4 v0 = r0[idx], v1 = r1[idx], vb = bb[idx];
        float s;
        s = v0.x + v1.x + vb.x; acc += s * s;
        s = v0.y + v1.y + vb.y; acc += s * s;
        s = v0.z + v1.z + vb.z; acc += s * s;
        s = v0.w + v1.w + vb.w; acc += s * s;
    }
#pragma unroll
    for (int off = 32; off > 0; off >>= 1) acc += __shfl_xor(acc, off);
    if (lane == 0) pp[wave] = acc;
}

// kFD: fused kB+kC at EXACT R4-kB geometry. 1024 blocks x 512 threads,
// 16 rows/block. Phase1: stage x bf16 swizzled + rb->LDS (byte-identical to
// proven kB). Phase2: MFMA, wave w owns col-tile w, U-tile -> LDS (8 KB).
// Phase3: epilogue, wave w streams rows {2w, 2w+1}; U/rb from LDS, pp from
// L2. Eliminates kB launch + U/rb round-trips. Ab traffic stays 128 MB.
__global__ __launch_bounds__(512) void kFD(const float* __restrict__ x,
                                           const u16* __restrict__ Ab,
                                           const float* __restrict__ bm,
                                           const float* __restrict__ pp,
                                           float* __restrict__ out) {
    __shared__ u16   xsb[16 * 512];    // 16 KB swizzled bf16 slab
    __shared__ float Ut[16][NA];       // 8 KB
    __shared__ float xxs[16], ws2[16];
    __shared__ float rbl[16];
    int t = threadIdx.x;
    int lane = t & 63;
    int w = t >> 6;
    int m0 = blockIdx.x * 16;

    // ---- phase 1: staging + rb (identical to R4 kB)
    {
        int row = t >> 5;
        int c0 = (t & 31) * 4;
        const float* xrow = x + (size_t)(m0 + row) * DIM;
        float xx = 0.f, wdot = 0.f;
#pragma unroll
        for (int i = 0; i < 4; ++i) {
            int col = c0 + i * 128;
            float4 v = *(const float4*)(xrow + col);
            float4 b = *(const float4*)(bm + col);
            xx   += v.x * v.x + v.y * v.y + v.z * v.z + v.w * v.w;
            wdot += v.x * b.x + v.y * b.y + v.z * b.z + v.w * b.w;
            ushort4 hv;
            hv.x = f2bf(v.x); hv.y = f2bf(v.y); hv.z = f2bf(v.z); hv.w = f2bf(v.w);
            int byte = (row * 1024 + col * 2) ^ ((row & 7) << 4);
            *(ushort4*)((char*)xsb + byte) = hv;
        }
#pragma unroll
        for (int off = 16; off > 0; off >>= 1) {
            xx   += __shfl_xor(xx, off);
            wdot += __shfl_xor(wdot, off);
        }
        if ((t & 31) == 0) { xxs[row] = xx; ws2[row] = wdot; }
    }
    __syncthreads();
    if (t < 16) rbl[t] = xxs[t] - 2.0f * ws2[t];

    // ---- phase 2: MFMA (identical to R4 kB, dest = LDS)
    {
        int r = lane & 15, g = lane >> 4;
        int ct = w;
        f32x4 acc = (f32x4){0.f, 0.f, 0.f, 0.f};
        const u16* brow = Ab + (size_t)(ct * 16 + r) * DIM;
#pragma unroll
        for (int k0 = 0; k0 < 16; ++k0) {
            int byte = (r * 1024 + k0 * 64 + g * 16) ^ ((r & 7) << 4);
            s16x8 af = *(const s16x8*)((const char*)xsb + byte);
            s16x8 bf = *(const s16x8*)(brow + k0 * 32 + g * 8);
            acc = __builtin_amdgcn_mfma_f32_16x16x32_bf16(af, bf, acc, 0, 0, 0);
        }
        // C/D: col = lane&15 -> A-row (ct*16+r), row = g*4+reg -> x-row
#pragma unroll
        for (int rr = 0; rr < 4; ++rr)
            Ut[g * 4 + rr][ct * 16 + r] = acc[rr];
    }
    __syncthreads();

    // ---- phase 3: epilogue. Wave w streams rows {2w, 2w+1}.
    {
        int l4 = (lane & 15) * 4;
#pragma unroll
        for (int rl = 0; rl < 2; ++rl) {
            int row = w * 2 + rl;
            float base0 = rbl[row];
            const float* Ur = Ut[row];
            float4 v4 = *(const float4*)(Ur + NPG + l4);   // loop-invariant
            float c0 = -2.0f * v4.x, c1 = -2.0f * v4.y;
            float c2 = -2.0f * v4.z, c3 = -2.0f * v4.w;
            float* orow = out + (size_t)(m0 + row) * NPAIR;
#pragma unroll
            for (int i = 0; i < 16; ++i) {
                int idx = (i * 64 + lane) * 4;
                int j = idx >> 6;
                float s = base0 - 2.0f * Ur[j];
                float4 p4 = *(const float4*)(pp + idx);
                float4 o;
                o.x = s + p4.x + c0;
                o.y = s + p4.y + c1;
                o.z = s + p4.z + c2;
                o.w = s + p4.w + c3;
                *(float4*)(orow + idx) = o;
            }
        }
    }
}

extern "C" void kernel_launch(void* const* d_in, const int* in_sizes, int n_in,
                              void* d_out, int out_size, void* d_ws, size_t ws_size,
                              hipStream_t stream) {
    const float* x     = (const float*)d_in[0];   // [16384, 512]
    const float* proto = (const float*)d_in[1];   // [2, 64, 512] -> flat [128, 512]
    const float* Wmix  = (const float*)d_in[2];   // [512, 1024]
    const float* bmix  = (const float*)d_in[3];   // [512]
    float* out = (float*)d_out;

    float* ws = (float*)d_ws;
    float* Af = ws;                         // 65536 f32
    float* pp = ws + 65536;                 // 4096 f32
    u16*   Ab = (u16*)(ws + 65536 + 4096);  // 65536 bf16

    kA_mixA<<<512, 256, 0, stream>>>(proto, Wmix, Af, Ab);
    k2_pp  <<<1024, 256, 0, stream>>>(Af, bmix, pp);
    kFD    <<<1024, 512, 0, stream>>>(x, Ab, bmix, pp, out);
}